// Round 13
// baseline (141.459 us; speedup 1.0000x reference)
//
#include <hip/hip_runtime.h>

#define MM 4096
#define NN 4096
#define KK 4096
#define BM 256
#define BN 256
#define BK 64
#define NT (KK / BK)

typedef short          s16x8 __attribute__((ext_vector_type(8)));
typedef float          f32x4 __attribute__((ext_vector_type(4)));
typedef unsigned short us4   __attribute__((ext_vector_type(4)));
typedef unsigned short us8   __attribute__((ext_vector_type(8)));

#define MFMA16(a, b, c) __builtin_amdgcn_mfma_f32_16x16x32_bf16((a), (b), (c), 0, 0, 0)
#define SB0() __builtin_amdgcn_sched_barrier(0)
#define VMC(n)  asm volatile("s_waitcnt vmcnt(" #n ")" ::: "memory")

// ws layout (ushort elements): wh [0, 16.7M) | xt_lo [16.7M, 25.2M) | xt2 [25.2M, 33.6M)
#define XTLO_OFF ((size_t)MM * KK)
#define XT2_OFF  (XTLO_OFF + (size_t)16 * 128 * KK)

// ---------- helpers ----------

__device__ __forceinline__ unsigned short f2bf(float f) {
  unsigned int u = __float_as_uint(f);
  u += 0x7fffu + ((u >> 16) & 1u);
  return (unsigned short)(u >> 16);
}

__device__ __forceinline__ void gload16(const void* g, void* l) {
  __builtin_amdgcn_global_load_lds(
      (const __attribute__((address_space(1))) void*)g,
      (__attribute__((address_space(3))) void*)l, 16, 0, 0);
}

// ---------- kernel 1: fused preprocessing ----------
// blocks [0, 8192):  2:4 mask + binarize + cvt -> W_h bf16 (M x K)
// blocks [8192, 12288): x (K x N f32) -> x^T in dual layout:
//   panel p = n>>8, np = n&255
//   np < 128 : xt_lo[p][np][k]  row-major (KK stride)  -- staged via gload_lds
//   np >= 128: xt2 fragment-linear: entry(p, nt=(np-128)>>4, kb=k>>5) =
//              64 lanes x 16B; lane = (np&15) | (((k>>3)&3)<<4)

__global__ __launch_bounds__(256) void kpre(const float* __restrict__ w,
                                            const float* __restrict__ x,
                                            unsigned short* __restrict__ wh,
                                            unsigned short* __restrict__ xlo,
                                            unsigned short* __restrict__ x2) {
  __shared__ float tile[64][65];
  const int t = threadIdx.x;

  if (blockIdx.x < 8192) {
    int idx = blockIdx.x * 256 + t;
    const float4* p = (const float4*)w;
    float4 g0 = p[(size_t)idx * 2];
    float4 g1 = p[(size_t)idx * 2 + 1];
    float v[8] = {g0.x, g0.y, g0.z, g0.w, g1.x, g1.y, g1.z, g1.w};
    us8 o;
#pragma unroll
    for (int g = 0; g < 2; g++) {
      float av[4];
#pragma unroll
      for (int j = 0; j < 4; j++) av[j] = fabsf(v[g * 4 + j]);
#pragma unroll
      for (int j = 0; j < 4; j++) {
        int rank = 0;
#pragma unroll
        for (int k = 0; k < 4; k++) {
          if (k == j) continue;
          rank += (av[k] > av[j] || (av[k] == av[j] && k < j)) ? 1 : 0;
        }
        o[g * 4 + j] = (rank < 2 && v[g * 4 + j] > 0.0f) ? (unsigned short)0x3F80
                                                         : (unsigned short)0;
      }
    }
    *(us8*)(wh + (size_t)idx * 8) = o;
    return;
  }

  int bid2 = blockIdx.x - 8192;
  int bn = bid2 & 63;
  int bk = bid2 >> 6;
  int tc = (t & 15) << 2;
  int tr = t >> 4;
  const float* src = x + (size_t)(bk * 64 + tr) * NN + bn * 64 + tc;
#pragma unroll
  for (int i = 0; i < 4; i++) {
    float4 v = *(const float4*)(src + (size_t)i * 16 * NN);
    int r = tr + i * 16;
    tile[r][tc + 0] = v.x; tile[r][tc + 1] = v.y;
    tile[r][tc + 2] = v.z; tile[r][tc + 3] = v.w;
  }
  __syncthreads();
  const int k0 = bk * 64 + tc;
#pragma unroll
  for (int i = 0; i < 4; i++) {
    int nl = tr + i * 16;
    int n  = bn * 64 + nl;
    us4 o;
    o.x = f2bf(tile[tc + 0][nl]);
    o.y = f2bf(tile[tc + 1][nl]);
    o.z = f2bf(tile[tc + 2][nl]);
    o.w = f2bf(tile[tc + 3][nl]);
    int p  = n >> 8;
    int np = n & 255;
    if (np < 128) {
      *(us4*)(xlo + (size_t)(p * 128 + np) * KK + k0) = o;
    } else {
      int nt   = (np - 128) >> 4;
      int kb   = k0 >> 5;
      int lane = (np & 15) | (((k0 >> 3) & 3) << 4);
      size_t off = (((size_t)(p * 8 + nt) * 128 + kb) * 64 + lane) * 8 + (k0 & 7);
      *(us4*)(x2 + off) = o;
    }
  }
}

// ---------- kernel 2: 256x256 GEMM, B-hi fragments direct from L2 ----------
// 8 waves (2M x 4N), BK=64. LDS holds only A (dbuf 2x32K) + B-lo (dbuf 2x16K)
// = 96 KiB; b1 (cols 128-255 of the block) is read as wave-coalesced 1KB
// global loads from the fragment-linear xt2 (L2-resident: each XCD owns 2
// bni columns), prefetched ONE TILE ahead into registers -> its latency is
// fully drained by the end-of-tile VMC(0). LDS reads/tile drop 24->20/wave;
// single af-set (af-major quadrant order) keeps unified regs ~238 <= 256.

__global__ __launch_bounds__(512, 2) void kgemm(const unsigned short* __restrict__ A,
                                                const unsigned short* __restrict__ xlo,
                                                const unsigned short* __restrict__ x2,
                                                float* __restrict__ C) {
  __shared__ __align__(16) unsigned short lds[49152];  // A0|A1 (16384 ea) | B0|B1 (8192 ea)

  const int tid  = threadIdx.x;
  // XCD swizzle: each XCD owns 2 bni columns (b1 panel 2MB -> L2-resident).
  const int bid  = blockIdx.x;
  const int xcd  = bid & 7;
  const int j    = bid >> 3;               // 0..31
  const int bni  = xcd * 2 + (j & 1);      // 0..15
  const int bmi  = j >> 1;                 // 0..15
  const int lane = tid & 63;
  const int wave = tid >> 6;
  const int wm   = wave >> 2;
  const int wn   = wave & 3;
  const int llo  = lane & 15;
  const int lhi  = lane >> 4;

  // staging addresses (linear LDS dest; inverse-swizzled global source)
  const int srow  = tid >> 3;
  const int scol  = (tid & 7) << 3;
  const int scolz = scol ^ ((srow & 7) << 3);
  const unsigned short* ga = A + (size_t)(bmi * BM + srow) * KK + scolz;
  const unsigned short* gb = xlo + ((size_t)bni * 128 + srow) * KK + scolz;

  // fragment read offsets (swizzled, 0-conflict)
  const int swz  = (llo & 7) << 3;
  const int ok0  = (lhi * 8) ^ swz;
  const int ok1  = (32 + lhi * 8) ^ swz;
  const int arow = (wm * 128 + llo) * BK;
  const int brow = (wn * 32 + llo) * BK;

  // b1 global bases (element offsets into xt2)
  size_t b1base[2];
#pragma unroll
  for (int f = 0; f < 2; f++)
    b1base[f] = ((size_t)(bni * 8 + wn * 2 + f) * 128) * 512 + (size_t)lane * 8;

  f32x4 acc[8][4] = {};
  s16x8 af[4][2], b0f[2][2], b1A[2][2], b1B[2][2];

  auto stageA = [&](int buf, int t) {   // 4 gloads
    const unsigned short* p = ga + (size_t)t * BK;
    unsigned short* l = &lds[buf * 16384 + tid * 8];
#pragma unroll
    for (int h = 0; h < 4; h++)
      gload16(p + (size_t)h * 64 * KK, l + h * 4096);
  };
  auto stageBlo = [&](int buf, int t) { // 2 gloads
    const unsigned short* p = gb + (size_t)t * BK;
    unsigned short* l = &lds[32768 + buf * 8192 + tid * 8];
#pragma unroll
    for (int h = 0; h < 2; h++)
      gload16(p + (size_t)h * 64 * KK, l + h * 4096);
  };
  auto prefB1 = [&](s16x8 (&dst)[2][2], int t) {
#pragma unroll
    for (int f = 0; f < 2; f++)
#pragma unroll
      for (int ks = 0; ks < 2; ks++)
        dst[f][ks] = *(const s16x8*)(x2 + b1base[f] + ((size_t)t * 2 + ks) * 512);
  };
  auto readAFlo = [&](const unsigned short* sa_) {
#pragma unroll
    for (int m = 0; m < 4; m++) {
      af[m][0] = *(const s16x8*)(sa_ + arow + m * 16 * BK + ok0);
      af[m][1] = *(const s16x8*)(sa_ + arow + m * 16 * BK + ok1);
    }
  };
  auto readAFhi = [&](const unsigned short* sa_) {
#pragma unroll
    for (int m = 0; m < 4; m++) {
      af[m][0] = *(const s16x8*)(sa_ + arow + (64 + m * 16) * BK + ok0);
      af[m][1] = *(const s16x8*)(sa_ + arow + (64 + m * 16) * BK + ok1);
    }
  };
  auto readB0 = [&](const unsigned short* sb_) {
#pragma unroll
    for (int n = 0; n < 2; n++) {
      b0f[n][0] = *(const s16x8*)(sb_ + brow + n * 16 * BK + ok0);
      b0f[n][1] = *(const s16x8*)(sb_ + brow + n * 16 * BK + ok1);
    }
  };

  // prologue: tile 0 -> buf0; certify; prefetch b1(tile 0)
  stageA(0, 0); stageBlo(0, 0);
  VMC(0); SB0();
  __builtin_amdgcn_s_barrier(); SB0();
  prefB1(b1A, 0);

  auto body = [&](int cur, s16x8 (&b1C)[2][2], s16x8 (&b1N)[2][2], int t) {
    const unsigned short* sa = &lds[cur * 16384];
    const unsigned short* sb = &lds[32768 + cur * 8192];
    const int tn = (t + 1) & (NT - 1);

    // stage tile t+1 into buf^1 (readers retired: every tile-(t-1) read had a
    // consuming MFMA before barrier(t-1))
    stageA(cur ^ 1, tn); stageBlo(cur ^ 1, tn);
    SB0();
    prefB1(b1N, tn);               // L2 reads, drained by this tile's VMC(0)
    SB0();

    readAFlo(sa); readB0(sb);

    // Q00: af-lo x b0
    __builtin_amdgcn_s_setprio(1);
#pragma unroll
    for (int m = 0; m < 4; m++)
#pragma unroll
      for (int n = 0; n < 2; n++) {
        acc[m][n] = MFMA16(af[m][0], b0f[n][0], acc[m][n]);
        acc[m][n] = MFMA16(af[m][1], b0f[n][1], acc[m][n]);
      }
    __builtin_amdgcn_s_setprio(0);

    // Q01: af-lo x b1 (prefetched last tile; already landed)
    __builtin_amdgcn_s_setprio(1);
#pragma unroll
    for (int m = 0; m < 4; m++)
#pragma unroll
      for (int n = 0; n < 2; n++) {
        acc[m][2 + n] = MFMA16(af[m][0], b1C[n][0], acc[m][2 + n]);
        acc[m][2 + n] = MFMA16(af[m][1], b1C[n][1], acc[m][2 + n]);
      }
    __builtin_amdgcn_s_setprio(0);

    // af-hi into the same regs (WAR after Q01)
    readAFhi(sa);

    // Qa0: af-hi x b0
    __builtin_amdgcn_s_setprio(1);
#pragma unroll
    for (int m = 0; m < 4; m++)
#pragma unroll
      for (int n = 0; n < 2; n++) {
        acc[4 + m][n] = MFMA16(af[m][0], b0f[n][0], acc[4 + m][n]);
        acc[4 + m][n] = MFMA16(af[m][1], b0f[n][1], acc[4 + m][n]);
      }
    __builtin_amdgcn_s_setprio(0);

    // Qa1: af-hi x b1
    __builtin_amdgcn_s_setprio(1);
#pragma unroll
    for (int m = 0; m < 4; m++)
#pragma unroll
      for (int n = 0; n < 2; n++) {
        acc[4 + m][2 + n] = MFMA16(af[m][0], b1C[n][0], acc[4 + m][2 + n]);
        acc[4 + m][2 + n] = MFMA16(af[m][1], b1C[n][1], acc[4 + m][2 + n]);
      }
    __builtin_amdgcn_s_setprio(0);

    // certify buf^1 (stage + b1N both drained); all LDS reads already consumed
    VMC(0); SB0();
    __builtin_amdgcn_s_barrier(); SB0();
  };

  for (int it = 0; it < NT / 2; ++it) {
    body(0, b1A, b1B, 2 * it);
    body(1, b1B, b1A, 2 * it + 1);
  }

  // ---- epilogue: D layout col = lane&15, row = (lane>>4)*4 + reg ----
  // cols: n<2 -> wn*32 + n*16 ; n>=2 -> 128 + wn*32 + (n-2)*16
  const int crow0 = bmi * BM + wm * 128 + lhi * 4;
#pragma unroll
  for (int m = 0; m < 8; m++)
#pragma unroll
    for (int n = 0; n < 4; n++) {
      int ccol = bni * BN + (n < 2 ? wn * 32 + n * 16 : 128 + wn * 32 + (n - 2) * 16) + llo;
      float* cp = C + (size_t)(crow0 + m * 16) * NN + ccol;
#pragma unroll
      for (int v = 0; v < 4; v++) cp[(size_t)v * NN] = acc[m][n][v];
    }
}

// ---------- fallback: fused fp32 tiled GEMM (workspace too small) ----------

__device__ __forceinline__ float binq_elem(const float g[4], int j) {
  float aj = fabsf(g[j]);
  int rank = 0;
#pragma unroll
  for (int k = 0; k < 4; k++) {
    if (k == j) continue;
    float ak = fabsf(g[k]);
    rank += (ak > aj || (ak == aj && k < j)) ? 1 : 0;
  }
  return (rank < 2 && g[j] > 0.0f) ? 1.0f : 0.0f;
}

__global__ __launch_bounds__(256) void kfallback(const float* __restrict__ x,
                                                 const float* __restrict__ w,
                                                 float* __restrict__ c) {
  __shared__ float sA[16][17];
  __shared__ float sB[16][17];
  int tx = threadIdx.x, ty = threadIdx.y;
  int row = blockIdx.y * 16 + ty;
  int col = blockIdx.x * 16 + tx;
  float acc = 0.0f;
  for (int k0 = 0; k0 < KK; k0 += 16) {
    int k = k0 + tx;
    const float* g = &w[(size_t)row * KK + (k & ~3)];
    float gv[4] = {g[0], g[1], g[2], g[3]};
    sA[ty][tx] = binq_elem(gv, k & 3);
    sB[ty][tx] = x[(size_t)(k0 + ty) * NN + col];
    __syncthreads();
#pragma unroll
    for (int kk = 0; kk < 16; kk++) acc += sA[ty][kk] * sB[kk][tx];
    __syncthreads();
  }
  c[(size_t)row * NN + col] = acc;
}

// ---------- launcher ----------

extern "C" void kernel_launch(void* const* d_in, const int* in_sizes, int n_in,
                              void* d_out, int out_size, void* d_ws, size_t ws_size,
                              hipStream_t stream) {
  const float* x = (const float*)d_in[0];
  const float* w = (const float*)d_in[1];
  float* out = (float*)d_out;

  const size_t need = (XT2_OFF + (size_t)16 * 128 * KK) * 2;  // 64 MB
  if (ws_size < need) {
    dim3 blk(16, 16);
    dim3 grd(NN / 16, MM / 16);
    kfallback<<<grd, blk, 0, stream>>>(x, w, out);
    return;
  }

  unsigned short* wh  = (unsigned short*)d_ws;
  unsigned short* xlo = wh + XTLO_OFF;
  unsigned short* x2  = wh + XT2_OFF;

  kpre<<<12288, 256, 0, stream>>>(w, x, wh, xlo, x2);
  kgemm<<<dim3(256), 512, 0, stream>>>(wh, xlo, x2, out);
}

// Round 15
// 128.942 us; speedup vs baseline: 1.0971x; 1.0971x over previous
//
#include <hip/hip_runtime.h>

#define MM 4096
#define NN 4096
#define KK 4096
#define BM 256
#define BN 256
#define BK 64
#define NT (KK / BK)

typedef short          s16x8 __attribute__((ext_vector_type(8)));
typedef float          f32x4 __attribute__((ext_vector_type(4)));
typedef unsigned short us4   __attribute__((ext_vector_type(4)));
typedef unsigned short us8   __attribute__((ext_vector_type(8)));

#define MFMA16(a, b, c) __builtin_amdgcn_mfma_f32_16x16x32_bf16((a), (b), (c), 0, 0, 0)
#define SB0() __builtin_amdgcn_sched_barrier(0)
#define LGKM(n) asm volatile("s_waitcnt lgkmcnt(" #n ")" ::: "memory")
#define VMC(n)  asm volatile("s_waitcnt vmcnt(" #n ")" ::: "memory")

// ---------- helpers ----------

__device__ __forceinline__ unsigned short f2bf(float f) {
  unsigned int u = __float_as_uint(f);
  u += 0x7fffu + ((u >> 16) & 1u);
  return (unsigned short)(u >> 16);
}

__device__ __forceinline__ void gload16(const void* g, void* l) {
  __builtin_amdgcn_global_load_lds(
      (const __attribute__((address_space(1))) void*)g,
      (__attribute__((address_space(3))) void*)l, 16, 0, 0);
}

// ---------- kernel 1: fused preprocessing ----------
// blocks [0, 8192):  2:4 mask + binarize + cvt -> W_h bf16 (M x K)
// blocks [8192, 12288): x (K x N f32) -> xT (N x K bf16), 64x64 LDS transpose

__global__ __launch_bounds__(256) void kpre(const float* __restrict__ w,
                                            const float* __restrict__ x,
                                            unsigned short* __restrict__ wh,
                                            unsigned short* __restrict__ xt) {
  __shared__ float tile[64][65];
  const int t = threadIdx.x;

  if (blockIdx.x < 8192) {
    // ---- quant path ----
    int idx = blockIdx.x * 256 + t;
    const float4* p = (const float4*)w;
    float4 g0 = p[(size_t)idx * 2];
    float4 g1 = p[(size_t)idx * 2 + 1];
    float v[8] = {g0.x, g0.y, g0.z, g0.w, g1.x, g1.y, g1.z, g1.w};
    us8 o;
#pragma unroll
    for (int g = 0; g < 2; g++) {
      float av[4];
#pragma unroll
      for (int j = 0; j < 4; j++) av[j] = fabsf(v[g * 4 + j]);
#pragma unroll
      for (int j = 0; j < 4; j++) {
        int rank = 0;
#pragma unroll
        for (int k = 0; k < 4; k++) {
          if (k == j) continue;
          rank += (av[k] > av[j] || (av[k] == av[j] && k < j)) ? 1 : 0;
        }
        o[g * 4 + j] = (rank < 2 && v[g * 4 + j] > 0.0f) ? (unsigned short)0x3F80
                                                         : (unsigned short)0;
      }
    }
    *(us8*)(wh + (size_t)idx * 8) = o;
    return;
  }

  // ---- transpose path ----
  int bid2 = blockIdx.x - 8192;
  int bn = bid2 & 63;
  int bk = bid2 >> 6;
  int tc = (t & 15) << 2;
  int tr = t >> 4;
  const float* src = x + (size_t)(bk * 64 + tr) * NN + bn * 64 + tc;
#pragma unroll
  for (int i = 0; i < 4; i++) {
    float4 v = *(const float4*)(src + (size_t)i * 16 * NN);
    int r = tr + i * 16;
    tile[r][tc + 0] = v.x; tile[r][tc + 1] = v.y;
    tile[r][tc + 2] = v.z; tile[r][tc + 3] = v.w;
  }
  __syncthreads();
  unsigned short* dst = xt + (size_t)(bn * 64 + tr) * KK + bk * 64 + tc;
#pragma unroll
  for (int i = 0; i < 4; i++) {
    int n = tr + i * 16;
    us4 o;
    o.x = f2bf(tile[tc + 0][n]);
    o.y = f2bf(tile[tc + 1][n]);
    o.z = f2bf(tile[tc + 2][n]);
    o.w = f2bf(tile[tc + 3][n]);
    *(us4*)(dst + (size_t)i * 16 * KK) = o;
  }
}

// ---------- kernel 2: 256x256 GEMM, balanced 12/12 read split (FIXED) -----
// r14's WAR bug: readAF(sa_n) was issued before Q01 which still consumes af.
// Fixed second-half order: readB0(sb_n) -> LGKM(4) [retires b1] -> Q01(af*b1)
// -> readAF(sa_n) [af now dead] -> Q11(af2*b1). Each half-tile carries 12
// ds_reads under 32 MFMA (vs r11's 0/24 lopsided split).
// Per-wave ledger (in-order DS retire):
//   top: out=12 {lo of t}; +12 {af2,b1 of t} -> out=24
//   LGKM(12) => lo ready -> Q00 ; LGKM(4) => af2 ready -> Q10
//   VMC(0)+barrier (buf^1 certified)
//   +4 {b0 of t+1} -> out=8 ; LGKM(4) => b1 ready -> Q01
//   +8 {af of t+1} -> out=12 ; Q11 ; loop (invariant restored)

__global__ __launch_bounds__(512, 2) void kgemm(const unsigned short* __restrict__ A,
                                                const unsigned short* __restrict__ B,
                                                float* __restrict__ C) {
  __shared__ __align__(16) unsigned short lds[4 * BM * BK];  // A0|A1|B0|B1, 128 KiB

  const int tid  = threadIdx.x;
  // XCD swizzle: xcd = bid&7; each XCD owns a 4x8 rectangle of the 16x16 grid.
  const int bid  = blockIdx.x;
  const int xcd  = bid & 7;
  const int j    = bid >> 3;
  const int bmi  = (xcd >> 1) * 4 + (j >> 3);
  const int bni  = (xcd & 1) * 8 + (j & 7);
  const int lane = tid & 63;
  const int wave = tid >> 6;
  const int wm   = wave >> 2;
  const int wn   = wave & 3;
  const int llo  = lane & 15;
  const int lhi  = lane >> 4;

  // staging addresses (linear LDS dest; inverse-swizzled global source)
  const int srow  = tid >> 3;
  const int scol  = (tid & 7) << 3;
  const int scolz = scol ^ ((srow & 7) << 3);
  const unsigned short* ga = A + (size_t)(bmi * BM + srow) * KK + scolz;
  const unsigned short* gb = B + (size_t)(bni * BN + srow) * KK + scolz;

  // fragment read offsets (swizzled) — proven 0-conflict pattern
  const int swz  = (llo & 7) << 3;
  const int ok0  = (lhi * 8) ^ swz;
  const int ok1  = (32 + lhi * 8) ^ swz;
  const int arow = (wm * 128 + llo) * BK;
  const int brow = (wn * 64 + llo) * BK;

  f32x4 acc[8][4] = {};
  s16x8 af[4][2], af2[4][2], b0[2][2], b1[2][2];

  auto stageA = [&](int buf, int t, int h) {
    const unsigned short* p = ga + (size_t)t * BK;
    unsigned short* l = &lds[buf * 16384 + tid * 8];
#pragma unroll
    for (int jj = 0; jj < 2; jj++)
      gload16(p + (size_t)(2 * h + jj) * 64 * KK, l + (2 * h + jj) * 4096);
  };
  auto stageB = [&](int buf, int t, int h) {
    const unsigned short* p = gb + (size_t)t * BK;
    unsigned short* l = &lds[32768 + buf * 16384 + tid * 8];
#pragma unroll
    for (int jj = 0; jj < 2; jj++)
      gload16(p + (size_t)(2 * h + jj) * 64 * KK, l + (2 * h + jj) * 4096);
  };

  auto readB0 = [&](const unsigned short* sb_) {   // 4 reads
#pragma unroll
    for (int n = 0; n < 2; n++) {
      b0[n][0] = *(const s16x8*)(sb_ + brow + n * 16 * BK + ok0);
      b0[n][1] = *(const s16x8*)(sb_ + brow + n * 16 * BK + ok1);
    }
  };
  auto readB1 = [&](const unsigned short* sb_) {   // 4 reads
#pragma unroll
    for (int n = 0; n < 2; n++) {
      b1[n][0] = *(const s16x8*)(sb_ + brow + (32 + n * 16) * BK + ok0);
      b1[n][1] = *(const s16x8*)(sb_ + brow + (32 + n * 16) * BK + ok1);
    }
  };
  auto readAF = [&](const unsigned short* sa_) {   // 8 reads
#pragma unroll
    for (int m = 0; m < 4; m++) {
      af[m][0] = *(const s16x8*)(sa_ + arow + m * 16 * BK + ok0);
      af[m][1] = *(const s16x8*)(sa_ + arow + m * 16 * BK + ok1);
    }
  };
  auto readAF2 = [&](const unsigned short* sa_) {  // 8 reads
#pragma unroll
    for (int m = 0; m < 4; m++) {
      af2[m][0] = *(const s16x8*)(sa_ + arow + (64 + m * 16) * BK + ok0);
      af2[m][1] = *(const s16x8*)(sa_ + arow + (64 + m * 16) * BK + ok1);
    }
  };

  // prologue: tile 0 -> buf0; certify; issue lo-half reads of tile 0 (12 out)
  stageA(0, 0, 0); stageA(0, 0, 1);
  stageB(0, 0, 0); stageB(0, 0, 1);
  VMC(0); SB0();
  __builtin_amdgcn_s_barrier(); SB0();
  readAF(&lds[0]); readB0(&lds[32768]); SB0();

  for (int t = 0; t < NT; ++t) {
    const int cur = t & 1;
    const unsigned short* sa   = &lds[cur * 16384];
    const unsigned short* sb   = &lds[32768 + cur * 16384];
    const unsigned short* sa_n = &lds[(cur ^ 1) * 16384];
    const unsigned short* sb_n = &lds[32768 + (cur ^ 1) * 16384];
    const int tn = (t + 1) & (NT - 1);   // wraps on last iter (dead loads/reads)

    // ===== first half =====
    // stage tile t+1 into buf^1 (its readers retired during tile t-1)
    stageA(cur ^ 1, tn, 0); stageA(cur ^ 1, tn, 1);
    stageB(cur ^ 1, tn, 0); stageB(cur ^ 1, tn, 1);
    SB0();
    // hi-half reads of THIS tile (buf cur certified at t-1 mid-barrier);
    // af2 before b1 (LGKM(4) count relies on it)
    readAF2(sa); SB0();
    readB1(sb); SB0();

    // gate lo reads of t (issued during t-1 second half)
    LGKM(12); SB0();

    // Q00: af x b0
    __builtin_amdgcn_s_setprio(1);
#pragma unroll
    for (int m = 0; m < 4; m++)
#pragma unroll
      for (int n = 0; n < 2; n++) {
        acc[m][n] = MFMA16(af[m][0], b0[n][0], acc[m][n]);
        acc[m][n] = MFMA16(af[m][1], b0[n][1], acc[m][n]);
      }
    __builtin_amdgcn_s_setprio(0);
    SB0();

    // gate af2 (leaves b1's 4 outstanding)
    LGKM(4); SB0();

    // Q10: af2 x b0  (b0 dead after this)
    __builtin_amdgcn_s_setprio(1);
#pragma unroll
    for (int m = 0; m < 4; m++)
#pragma unroll
      for (int n = 0; n < 2; n++) {
        acc[4 + m][n] = MFMA16(af2[m][0], b0[n][0], acc[4 + m][n]);
        acc[4 + m][n] = MFMA16(af2[m][1], b0[n][1], acc[4 + m][n]);
      }
    __builtin_amdgcn_s_setprio(0);
    SB0();

    // certify buf^1 (stage issued at tile top: full first half of cover)
    VMC(0); SB0();
    __builtin_amdgcn_s_barrier(); SB0();

    // ===== second half =====
    // b0 of tile t+1 into freed b0 regs (drains under Q01)
    readB0(sb_n); SB0();

    // gate b1(t): out = b1(4)+b0n(4); LGKM(4) retires the 4 oldest = b1
    LGKM(4); SB0();

    // Q01: af x b1  (af dead after this)
    __builtin_amdgcn_s_setprio(1);
#pragma unroll
    for (int m = 0; m < 4; m++)
#pragma unroll
      for (int n = 0; n < 2; n++) {
        acc[m][2 + n] = MFMA16(af[m][0], b1[n][0], acc[m][2 + n]);
        acc[m][2 + n] = MFMA16(af[m][1], b1[n][1], acc[m][2 + n]);
      }
    __builtin_amdgcn_s_setprio(0);
    SB0();

    // af of tile t+1 into freed af regs (drains under Q11)
    readAF(sa_n); SB0();

    // Q11: af2 x b1  (af2, b1 dead after this)
    __builtin_amdgcn_s_setprio(1);
#pragma unroll
    for (int m = 0; m < 4; m++)
#pragma unroll
      for (int n = 0; n < 2; n++) {
        acc[4 + m][2 + n] = MFMA16(af2[m][0], b1[n][0], acc[4 + m][2 + n]);
        acc[4 + m][2 + n] = MFMA16(af2[m][1], b1[n][1], acc[4 + m][2 + n]);
      }
    __builtin_amdgcn_s_setprio(0);
    SB0();
  }

  // ---- epilogue: D layout col = lane&15, row = (lane>>4)*4 + reg ----
  const int crow0 = bmi * BM + wm * 128 + lhi * 4;
  const int ccol0 = bni * BN + wn * 64 + llo;
#pragma unroll
  for (int m = 0; m < 8; m++)
#pragma unroll
    for (int n = 0; n < 4; n++) {
      float* cp = C + (size_t)(crow0 + m * 16) * NN + ccol0 + n * 16;
#pragma unroll
      for (int v = 0; v < 4; v++) cp[(size_t)v * NN] = acc[m][n][v];
    }
}

// ---------- fallback: fused fp32 tiled GEMM (workspace too small) ----------

__device__ __forceinline__ float binq_elem(const float g[4], int j) {
  float aj = fabsf(g[j]);
  int rank = 0;
#pragma unroll
  for (int k = 0; k < 4; k++) {
    if (k == j) continue;
    float ak = fabsf(g[k]);
    rank += (ak > aj || (ak == aj && k < j)) ? 1 : 0;
  }
  return (rank < 2 && g[j] > 0.0f) ? 1.0f : 0.0f;
}

__global__ __launch_bounds__(256) void kfallback(const float* __restrict__ x,
                                                 const float* __restrict__ w,
                                                 float* __restrict__ c) {
  __shared__ float sA[16][17];
  __shared__ float sB[16][17];
  int tx = threadIdx.x, ty = threadIdx.y;
  int row = blockIdx.y * 16 + ty;
  int col = blockIdx.x * 16 + tx;
  float acc = 0.0f;
  for (int k0 = 0; k0 < KK; k0 += 16) {
    int k = k0 + tx;
    const float* g = &w[(size_t)row * KK + (k & ~3)];
    float gv[4] = {g[0], g[1], g[2], g[3]};
    sA[ty][tx] = binq_elem(gv, k & 3);
    sB[ty][tx] = x[(size_t)(k0 + ty) * NN + col];
    __syncthreads();
#pragma unroll
    for (int kk = 0; kk < 16; kk++) acc += sA[ty][kk] * sB[kk][tx];
    __syncthreads();
  }
  c[(size_t)row * NN + col] = acc;
}

// ---------- launcher ----------

extern "C" void kernel_launch(void* const* d_in, const int* in_sizes, int n_in,
                              void* d_out, int out_size, void* d_ws, size_t ws_size,
                              hipStream_t stream) {
  const float* x = (const float*)d_in[0];
  const float* w = (const float*)d_in[1];
  float* out = (float*)d_out;

  const size_t need = (size_t)MM * KK * 2 + (size_t)NN * KK * 2;
  if (ws_size < need) {
    dim3 blk(16, 16);
    dim3 grd(NN / 16, MM / 16);
    kfallback<<<grd, blk, 0, stream>>>(x, w, out);
    return;
  }

  unsigned short* wh = (unsigned short*)d_ws;
  unsigned short* xt = wh + (size_t)MM * KK;

  kpre<<<12288, 256, 0, stream>>>(w, x, wh, xt);
  kgemm<<<dim3((MM / BM) * (NN / BN)), 512, 0, stream>>>(wh, xt, out);
}